// Round 5
// baseline (340.214 us; speedup 1.0000x reference)
//
#include <hip/hip_runtime.h>
#include <stdint.h>

typedef __bf16 bf16;
typedef __bf16 bf16x8 __attribute__((ext_vector_type(8)));
typedef __bf16 bf16x4 __attribute__((ext_vector_type(4)));
typedef float f32x4 __attribute__((ext_vector_type(4)));

#define NSEQ 1032
#define BATCH 8
#define NHEADS 12
#define HD 64
#define CDIM 768
#define MROWS (BATCH * NSEQ)   // 8256
#define PREFIX 8
#define BQ_ROWS 1152
#define BK_COLS 1088
#define SKP 66                 // padded LDS cols: 33 dwords = 1 mod 32 banks

__device__ __forceinline__ unsigned short f2bf_rne(float f) {
    union { float f; uint32_t u; } v; v.f = f;
    uint32_t u = v.u;
    return (unsigned short)((u + 0x7fffu + ((u >> 16) & 1u)) >> 16);
}

__device__ __forceinline__ void gload_lds16(const bf16* g, bf16* l) {
    __builtin_amdgcn_global_load_lds(
        (const __attribute__((address_space(1))) void*)g,
        (__attribute__((address_space(3))) void*)l, 16, 0, 0);
}

__device__ __forceinline__ void cast4(const float* src, bf16* dst, int i) {
    float4 f = ((const float4*)src)[i];
    ushort4 o;
    o.x = f2bf_rne(f.x); o.y = f2bf_rne(f.y);
    o.z = f2bf_rne(f.z); o.w = f2bf_rne(f.w);
    ((ushort4*)dst)[i] = o;
}

// Fused prep: bias table + x/qkv_w(kv)/proj_w casts in one launch.
__global__ void prep_kernel(const float* __restrict__ x,
                            const float* __restrict__ wkv,
                            const float* __restrict__ pw,
                            bf16* __restrict__ x_bf, bf16* __restrict__ wkv_bf,
                            bf16* __restrict__ pw_bf, float* __restrict__ Bias) {
    const int N0 = BQ_ROWS * BK_COLS;
    const int N1 = MROWS * CDIM / 4;
    const int N2 = 2 * CDIM * CDIM / 4;
    const int N3 = CDIM * CDIM / 4;
    int i = blockIdx.x * blockDim.x + threadIdx.x;
    if (i < N0) {
        int q = i / BK_COLS, k = i % BK_COLS;
        float v;
        if (k >= NSEQ) v = -1e30f;
        else if (q < PREFIX || q >= NSEQ || k < PREFIX) v = 0.f;
        else {
            int rp = q - PREFIX, cp = k - PREFIX;
            int d1 = (rp >> 5) - (cp >> 5);
            int d2 = (rp & 31) - (cp & 31);
            v = __expf(-0.02f * (float)(d1 * d1 + d2 * d2));
        }
        Bias[i] = v;
        return;
    }
    i -= N0;
    if (i < N1) { cast4(x, x_bf, i); return; }
    i -= N1;
    if (i < N2) { cast4(wkv, wkv_bf, i); return; }
    i -= N2;
    if (i < N3) { cast4(pw, pw_bf, i); }
}

// NT GEMM, m97-style DMA staging (unchanged from round 4).
template<int EPI>
__global__ __launch_bounds__(256) void gemm_nt(
    const bf16* __restrict__ A, const bf16* __restrict__ B,
    const float* __restrict__ bias,
    float* __restrict__ Cout, bf16* __restrict__ Kout, bf16* __restrict__ VTout,
    int M, int N, int K)
{
    __shared__ bf16 sA[128 * 32];
    __shared__ bf16 sB[128 * 32];
    const int t = threadIdx.x;
    const int w = t >> 6;
    const int l = t & 63;
    const int quad = l >> 4;
    const int l15 = l & 15;
    const int wy = w >> 1, wx = w & 1;
    const int m0 = blockIdx.y * 128;
    const int n0 = blockIdx.x * 128;
    const int co = (quad ^ ((l15 >> 1) & 3)) * 8;

    int r0 = t >> 2,          c0 = (t & 3) ^ ((r0 >> 1) & 3);
    int r1 = (t + 256) >> 2,  c1 = ((t + 256) & 3) ^ ((r1 >> 1) & 3);
    int ra0 = m0 + r0; if (ra0 >= M) ra0 = M - 1;
    int ra1 = m0 + r1; if (ra1 >= M) ra1 = M - 1;
    const bf16* gA0 = A + (size_t)ra0 * K + c0 * 8;
    const bf16* gA1 = A + (size_t)ra1 * K + c1 * 8;
    const bf16* gB0 = B + (size_t)(n0 + r0) * K + c0 * 8;
    const bf16* gB1 = B + (size_t)(n0 + r1) * K + c1 * 8;
    bf16* dA0 = &sA[(size_t)(w * 64) * 8];
    bf16* dA1 = &sA[(size_t)(256 + w * 64) * 8];
    bf16* dB0 = &sB[(size_t)(w * 64) * 8];
    bf16* dB1 = &sB[(size_t)(256 + w * 64) * 8];

    f32x4 acc[4][4] = {};

    for (int k0 = 0; k0 < K; k0 += 32) {
        __syncthreads();
        gload_lds16(gA0, dA0); gload_lds16(gA1, dA1);
        gload_lds16(gB0, dB0); gload_lds16(gB1, dB1);
        gA0 += 32; gA1 += 32; gB0 += 32; gB1 += 32;
        __syncthreads();
        bf16x8 af[4], bq[4];
        #pragma unroll
        for (int mt = 0; mt < 4; ++mt)
            af[mt] = *(const bf16x8*)&sA[(wy*64 + mt*16 + l15) * 32 + co];
        #pragma unroll
        for (int nt = 0; nt < 4; ++nt)
            bq[nt] = *(const bf16x8*)&sB[(wx*64 + nt*16 + l15) * 32 + co];
        #pragma unroll
        for (int mt = 0; mt < 4; ++mt)
            #pragma unroll
            for (int nt = 0; nt < 4; ++nt)
                acc[mt][nt] = __builtin_amdgcn_mfma_f32_16x16x32_bf16(af[mt], bq[nt], acc[mt][nt], 0, 0, 0);
    }

    #pragma unroll
    for (int mt = 0; mt < 4; ++mt) {
        #pragma unroll
        for (int r = 0; r < 4; ++r) {
            int m = m0 + wy*64 + mt*16 + quad*4 + r;
            if (m >= M) continue;
            #pragma unroll
            for (int nt = 0; nt < 4; ++nt) {
                int n = n0 + wx*64 + nt*16 + l15;
                float v = acc[mt][nt][r] + bias[n];
                if (EPI == 0) {
                    Cout[(size_t)m * N + n] = v;
                } else {
                    int b = m / NSEQ, s = m % NSEQ;
                    if (n < CDIM) {
                        int h = n >> 6, d = n & 63;
                        Kout[(((size_t)(b*NHEADS + h))*NSEQ + s)*HD + d] = (bf16)(v * 0.35355339f);
                    } else {
                        int n2 = n - CDIM;
                        int h = n2 >> 6, d = n2 & 63;
                        VTout[(((size_t)(b*NHEADS + h))*HD + d)*NSEQ + s] = (bf16)v;
                    }
                }
            }
        }
    }
}

// Attention: 4 waves x 32 q-rows (256 thr), j-tile 64, register-prefetch
// pipeline, all LDS padded to 66 cols (~2-way banks). grid = (bh, qtile).
__global__ __launch_bounds__(256, 3) void attn_kernel(
    const bf16* __restrict__ Kbuf, const bf16* __restrict__ VTbuf,
    const float* __restrict__ Bias, bf16* __restrict__ Hout)
{
    const int bh = blockIdx.x;
    const int b = bh / NHEADS, h = bh % NHEADS;
    const int q0 = blockIdx.y * 128;
    const bf16* Kh  = Kbuf  + (size_t)bh * NSEQ * HD;
    const bf16* VTh = VTbuf + (size_t)bh * HD * NSEQ;

    __shared__ bf16 sK[64][SKP];
    __shared__ bf16 sVT[64][SKP];
    __shared__ bf16 sP[128][SKP];
    __shared__ float sL[128];

    const int t = threadIdx.x;
    const int w = t >> 6, l = t & 63, quad = l >> 4, l15 = l & 15;

    // Q fragments in registers (B-operand; 32 query rows per wave)
    bf16x8 qf[2][2];
    #pragma unroll
    for (int mt = 0; mt < 2; ++mt) {
        int row = q0 + w*32 + mt*16 + l15;
        if (row > NSEQ - 1) row = NSEQ - 1;
        #pragma unroll
        for (int ks = 0; ks < 2; ++ks)
            qf[mt][ks] = *(const bf16x8*)&Kh[(size_t)row * HD + ks*32 + quad*8];
    }

    int qg[2];
    qg[0] = q0 + w*32 + l15;
    qg[1] = qg[0] + 16;
    const int srow = t >> 3;          // 0..31
    const int scol = (t & 7) * 8;     // 0..56

    f32x4 Oacc[2][4] = {};
    float ps[2][4] = {};

    uint4 kv[2], vv[2];
    f32x4 bias_pf[2][4];

    // initial prefetch (tile 0)
    kv[0] = *(const uint4*)&Kh[(size_t)srow * HD + scol];
    kv[1] = *(const uint4*)&Kh[(size_t)(srow + 32) * HD + scol];
    vv[0] = *(const uint4*)&VTh[(size_t)srow * NSEQ + scol];
    vv[1] = *(const uint4*)&VTh[(size_t)(srow + 32) * NSEQ + scol];
    #pragma unroll
    for (int mt = 0; mt < 2; ++mt)
        #pragma unroll
        for (int kt = 0; kt < 4; ++kt)
            bias_pf[mt][kt] = *(const f32x4*)&Bias[(size_t)qg[mt] * BK_COLS + kt*16 + quad*4];

    for (int j0 = 0; j0 < NSEQ; j0 += 64) {
        *(uint4*)&sK[srow][scol]       = kv[0];
        *(uint4*)&sK[srow + 32][scol]  = kv[1];
        *(uint4*)&sVT[srow][scol]      = vv[0];
        *(uint4*)&sVT[srow + 32][scol] = vv[1];
        f32x4 sacc[2][4];
        #pragma unroll
        for (int mt = 0; mt < 2; ++mt)
            #pragma unroll
            for (int kt = 0; kt < 4; ++kt) sacc[mt][kt] = bias_pf[mt][kt];
        __syncthreads();

        // prefetch next tile (consumed next iteration)
        {
            int jn = j0 + 64; if (jn >= NSEQ) jn = j0;
            int rk0 = jn + srow;      if (rk0 > NSEQ - 1) rk0 = NSEQ - 1;
            int rk1 = jn + srow + 32; if (rk1 > NSEQ - 1) rk1 = NSEQ - 1;
            kv[0] = *(const uint4*)&Kh[(size_t)rk0 * HD + scol];
            kv[1] = *(const uint4*)&Kh[(size_t)rk1 * HD + scol];
            int cs = jn + scol; if (cs > NSEQ - 8) cs = NSEQ - 8;
            vv[0] = *(const uint4*)&VTh[(size_t)srow * NSEQ + cs];
            vv[1] = *(const uint4*)&VTh[(size_t)(srow + 32) * NSEQ + cs];
            #pragma unroll
            for (int mt = 0; mt < 2; ++mt)
                #pragma unroll
                for (int kt = 0; kt < 4; ++kt)
                    bias_pf[mt][kt] = *(const f32x4*)&Bias[(size_t)qg[mt] * BK_COLS + jn + kt*16 + quad*4];
        }

        // S^T = K' * Q'^T
        #pragma unroll
        for (int ks = 0; ks < 2; ++ks) {
            bf16x8 af[4];
            #pragma unroll
            for (int kt = 0; kt < 4; ++kt)
                af[kt] = *(const bf16x8*)&sK[kt*16 + l15][ks*32 + quad*8];
            #pragma unroll
            for (int kt = 0; kt < 4; ++kt)
                #pragma unroll
                for (int mt = 0; mt < 2; ++mt)
                    sacc[mt][kt] = __builtin_amdgcn_mfma_f32_16x16x32_bf16(af[kt], qf[mt][ks], sacc[mt][kt], 0, 0, 0);
        }

        // P = exp(S); b64 stores (rows wave-private, 66-pad ~2-way banks)
        #pragma unroll
        for (int mt = 0; mt < 2; ++mt)
            #pragma unroll
            for (int kt = 0; kt < 4; ++kt) {
                float p0 = __expf(sacc[mt][kt][0]);
                float p1 = __expf(sacc[mt][kt][1]);
                float p2 = __expf(sacc[mt][kt][2]);
                float p3 = __expf(sacc[mt][kt][3]);
                ps[mt][kt] += (p0 + p1) + (p2 + p3);
                bf16x4 pv = { (bf16)p0, (bf16)p1, (bf16)p2, (bf16)p3 };
                *(bf16x4*)&sP[w*32 + mt*16 + l15][kt*16 + quad*4] = pv;
            }

        // O += P V
        #pragma unroll
        for (int ks = 0; ks < 2; ++ks) {
            bf16x8 ap[2], bv[4];
            #pragma unroll
            for (int mt = 0; mt < 2; ++mt)
                ap[mt] = *(const bf16x8*)&sP[w*32 + mt*16 + l15][ks*32 + quad*8];
            #pragma unroll
            for (int dt = 0; dt < 4; ++dt)
                bv[dt] = *(const bf16x8*)&sVT[dt*16 + l15][ks*32 + quad*8];
            #pragma unroll
            for (int mt = 0; mt < 2; ++mt)
                #pragma unroll
                for (int dt = 0; dt < 4; ++dt)
                    Oacc[mt][dt] = __builtin_amdgcn_mfma_f32_16x16x32_bf16(ap[mt], bv[dt], Oacc[mt][dt], 0, 0, 0);
        }
        __syncthreads();
    }

    // row sums
    #pragma unroll
    for (int mt = 0; mt < 2; ++mt) {
        float s = (ps[mt][0] + ps[mt][1]) + (ps[mt][2] + ps[mt][3]);
        s += __shfl_xor(s, 16, 64);
        s += __shfl_xor(s, 32, 64);
        if (l < 16) sL[w*32 + mt*16 + l] = s;
    }
    __syncthreads();

    #pragma unroll
    for (int mt = 0; mt < 2; ++mt) {
        #pragma unroll
        for (int r = 0; r < 4; ++r) {
            int g = q0 + w*32 + mt*16 + quad*4 + r;
            if (g >= NSEQ) continue;
            float inv = 1.f / sL[w*32 + mt*16 + quad*4 + r];
            size_t base = ((size_t)(b * NSEQ) + g) * CDIM + h * HD;
            #pragma unroll
            for (int dt = 0; dt < 4; ++dt)
                Hout[base + dt*16 + l15] = (bf16)(Oacc[mt][dt][r] * inv);
        }
    }
}

extern "C" void kernel_launch(void* const* d_in, const int* in_sizes, int n_in,
                              void* d_out, int out_size, void* d_ws, size_t ws_size,
                              hipStream_t stream) {
    const float* x      = (const float*)d_in[0];
    const float* qkv_w  = (const float*)d_in[1];
    const float* qkv_b  = (const float*)d_in[2];
    const float* proj_w = (const float*)d_in[3];
    const float* proj_b = (const float*)d_in[4];
    float* out = (float*)d_out;

    char* ws = (char*)d_ws;
    const size_t XBF_BYTES   = (size_t)MROWS * CDIM * 2;
    const size_t WKV_BYTES   = (size_t)2 * CDIM * CDIM * 2;
    const size_t PW_BYTES    = (size_t)CDIM * CDIM * 2;
    const size_t KBF_BYTES   = (size_t)BATCH * NHEADS * NSEQ * HD * 2;

    bf16* x_bf   = (bf16*)ws;
    bf16* wkv_bf = (bf16*)(ws + XBF_BYTES);
    bf16* pw_bf  = (bf16*)(ws + XBF_BYTES + WKV_BYTES);
    bf16* k_bf   = (bf16*)(ws + XBF_BYTES + WKV_BYTES + PW_BYTES);
    bf16* vT_bf  = (bf16*)(ws + XBF_BYTES + WKV_BYTES + PW_BYTES + KBF_BYTES);
    float* bias_t= (float*)(ws + XBF_BYTES + WKV_BYTES + PW_BYTES + KBF_BYTES + KBF_BYTES);

    // fused prep: bias table + all casts
    {
        int total = BQ_ROWS * BK_COLS + MROWS * CDIM / 4
                  + 2 * CDIM * CDIM / 4 + CDIM * CDIM / 4;
        prep_kernel<<<dim3((total + 255) / 256), dim3(256), 0, stream>>>(
            x, qkv_w + (size_t)CDIM * CDIM, proj_w, x_bf, wkv_bf, pw_bf, bias_t);
    }

    // qkv GEMM (k & v only): M=8256, N=1536, K=768
    {
        dim3 grid(1536 / 128, (MROWS + 127) / 128);
        gemm_nt<1><<<grid, dim3(256), 0, stream>>>(x_bf, wkv_bf, qkv_b + CDIM,
                                                   nullptr, k_bf, vT_bf,
                                                   MROWS, 1536, CDIM);
    }

    // attention -> hidden (reuse x_bf buffer); grid (bh, qtile) for XCD locality
    {
        dim3 grid(BATCH * NHEADS, (NSEQ + 127) / 128);
        attn_kernel<<<grid, dim3(256), 0, stream>>>(k_bf, vT_bf, bias_t, x_bf);
    }

    // proj GEMM: out = hidden @ proj_w^T + proj_b, fp32 out
    {
        dim3 grid(CDIM / 128, (MROWS + 127) / 128);
        gemm_nt<0><<<grid, dim3(256), 0, stream>>>(x_bf, pw_bf, proj_b,
                                                   out, nullptr, nullptr,
                                                   MROWS, CDIM, CDIM);
    }
}

// Round 6
// 250.341 us; speedup vs baseline: 1.3590x; 1.3590x over previous
//
#include <hip/hip_runtime.h>
#include <stdint.h>

typedef __bf16 bf16;
typedef __bf16 bf16x8 __attribute__((ext_vector_type(8)));
typedef __bf16 bf16x4 __attribute__((ext_vector_type(4)));
typedef float f32x4 __attribute__((ext_vector_type(4)));

#define NSEQ 1032
#define BATCH 8
#define NHEADS 12
#define HD 64
#define CDIM 768
#define MROWS (BATCH * NSEQ)   // 8256
#define PREFIX 8
#define BQ_ROWS 1152
#define BK_COLS 1088

__device__ __forceinline__ unsigned short f2bf_rne(float f) {
    union { float f; uint32_t u; } v; v.f = f;
    uint32_t u = v.u;
    return (unsigned short)((u + 0x7fffu + ((u >> 16) & 1u)) >> 16);
}

__device__ __forceinline__ void gload_lds16(const bf16* g, bf16* l) {
    __builtin_amdgcn_global_load_lds(
        (const __attribute__((address_space(1))) void*)g,
        (__attribute__((address_space(3))) void*)l, 16, 0, 0);
}

__device__ __forceinline__ void cast4(const float* src, bf16* dst, int i) {
    float4 f = ((const float4*)src)[i];
    ushort4 o;
    o.x = f2bf_rne(f.x); o.y = f2bf_rne(f.y);
    o.z = f2bf_rne(f.z); o.w = f2bf_rne(f.w);
    ((ushort4*)dst)[i] = o;
}

// Fused prep: bias table + x/qkv_w(kv)/proj_w casts in one launch.
__global__ void prep_kernel(const float* __restrict__ x,
                            const float* __restrict__ wkv,
                            const float* __restrict__ pw,
                            bf16* __restrict__ x_bf, bf16* __restrict__ wkv_bf,
                            bf16* __restrict__ pw_bf, float* __restrict__ Bias) {
    const int N0 = BQ_ROWS * BK_COLS;
    const int N1 = MROWS * CDIM / 4;
    const int N2 = 2 * CDIM * CDIM / 4;
    const int N3 = CDIM * CDIM / 4;
    int i = blockIdx.x * blockDim.x + threadIdx.x;
    if (i < N0) {
        int q = i / BK_COLS, k = i % BK_COLS;
        float v;
        if (k >= NSEQ) v = -1e30f;
        else if (q < PREFIX || q >= NSEQ || k < PREFIX) v = 0.f;
        else {
            int rp = q - PREFIX, cp = k - PREFIX;
            int d1 = (rp >> 5) - (cp >> 5);
            int d2 = (rp & 31) - (cp & 31);
            v = __expf(-0.02f * (float)(d1 * d1 + d2 * d2));
        }
        Bias[i] = v;
        return;
    }
    i -= N0;
    if (i < N1) { cast4(x, x_bf, i); return; }
    i -= N1;
    if (i < N2) { cast4(wkv, wkv_bf, i); return; }
    i -= N2;
    if (i < N3) { cast4(pw, pw_bf, i); }
}

// NT GEMM, m97-style DMA staging.
// EPI=0: fp32 out. EPI=1: n<768 -> K' (scaled sqrt(0.125)) [B,H,s,d];
//                         n>=768 -> V row-major [B,H,s,d].
template<int EPI>
__global__ __launch_bounds__(256) void gemm_nt(
    const bf16* __restrict__ A, const bf16* __restrict__ B,
    const float* __restrict__ bias,
    float* __restrict__ Cout, bf16* __restrict__ Kout, bf16* __restrict__ Vout,
    int M, int N, int K)
{
    __shared__ bf16 sA[128 * 32];
    __shared__ bf16 sB[128 * 32];
    const int t = threadIdx.x;
    const int w = t >> 6;
    const int l = t & 63;
    const int quad = l >> 4;
    const int l15 = l & 15;
    const int wy = w >> 1, wx = w & 1;
    const int m0 = blockIdx.y * 128;
    const int n0 = blockIdx.x * 128;
    const int co = (quad ^ ((l15 >> 1) & 3)) * 8;

    int r0 = t >> 2,          c0 = (t & 3) ^ ((r0 >> 1) & 3);
    int r1 = (t + 256) >> 2,  c1 = ((t + 256) & 3) ^ ((r1 >> 1) & 3);
    int ra0 = m0 + r0; if (ra0 >= M) ra0 = M - 1;
    int ra1 = m0 + r1; if (ra1 >= M) ra1 = M - 1;
    const bf16* gA0 = A + (size_t)ra0 * K + c0 * 8;
    const bf16* gA1 = A + (size_t)ra1 * K + c1 * 8;
    const bf16* gB0 = B + (size_t)(n0 + r0) * K + c0 * 8;
    const bf16* gB1 = B + (size_t)(n0 + r1) * K + c1 * 8;
    bf16* dA0 = &sA[(size_t)(w * 64) * 8];
    bf16* dA1 = &sA[(size_t)(256 + w * 64) * 8];
    bf16* dB0 = &sB[(size_t)(w * 64) * 8];
    bf16* dB1 = &sB[(size_t)(256 + w * 64) * 8];

    f32x4 acc[4][4] = {};

    for (int k0 = 0; k0 < K; k0 += 32) {
        __syncthreads();
        gload_lds16(gA0, dA0); gload_lds16(gA1, dA1);
        gload_lds16(gB0, dB0); gload_lds16(gB1, dB1);
        gA0 += 32; gA1 += 32; gB0 += 32; gB1 += 32;
        __syncthreads();
        bf16x8 af[4], bq[4];
        #pragma unroll
        for (int mt = 0; mt < 4; ++mt)
            af[mt] = *(const bf16x8*)&sA[(wy*64 + mt*16 + l15) * 32 + co];
        #pragma unroll
        for (int nt = 0; nt < 4; ++nt)
            bq[nt] = *(const bf16x8*)&sB[(wx*64 + nt*16 + l15) * 32 + co];
        #pragma unroll
        for (int mt = 0; mt < 4; ++mt)
            #pragma unroll
            for (int nt = 0; nt < 4; ++nt)
                acc[mt][nt] = __builtin_amdgcn_mfma_f32_16x16x32_bf16(af[mt], bq[nt], acc[mt][nt], 0, 0, 0);
    }

    #pragma unroll
    for (int mt = 0; mt < 4; ++mt) {
        #pragma unroll
        for (int r = 0; r < 4; ++r) {
            int m = m0 + wy*64 + mt*16 + quad*4 + r;
            if (m >= M) continue;
            #pragma unroll
            for (int nt = 0; nt < 4; ++nt) {
                int n = n0 + wx*64 + nt*16 + l15;
                float v = acc[mt][nt][r] + bias[n];
                if (EPI == 0) {
                    Cout[(size_t)m * N + n] = v;
                } else {
                    int b = m / NSEQ, s = m % NSEQ;
                    if (n < CDIM) {
                        int h = n >> 6, d = n & 63;
                        Kout[(((size_t)(b*NHEADS + h))*NSEQ + s)*HD + d] = (bf16)(v * 0.35355339f);
                    } else {
                        int n2 = n - CDIM;
                        int h = n2 >> 6, d = n2 & 63;
                        Vout[(((size_t)(b*NHEADS + h))*NSEQ + s)*HD + d] = (bf16)v;
                    }
                }
            }
        }
    }
}

// Attention (round-4 structure): 8 waves x 16 q-rows, j-tile 64, register
// prefetch pipeline. V arrives row-major and is transposed into sVT during
// LDS staging (column writes, 66-pad). sK 72-pad; sP 64-wide XOR-swizzled.
__global__ __launch_bounds__(512) void attn_kernel(
    const bf16* __restrict__ Kbuf, const bf16* __restrict__ Vbuf,
    const float* __restrict__ Bias, bf16* __restrict__ Hout)
{
    const int bh = blockIdx.x;                  // bh-major: XCD locality
    const int b = bh / NHEADS, h = bh % NHEADS;
    const int q0 = blockIdx.y * 128;
    const bf16* Kh = Kbuf + (size_t)bh * NSEQ * HD;
    const bf16* Vh = Vbuf + (size_t)bh * NSEQ * HD;

    __shared__ bf16 sK[64][72];
    __shared__ bf16 sVT[64][66];
    __shared__ bf16 sP[128 * 64];
    __shared__ float sL[128];

    const int t = threadIdx.x;
    const int w = t >> 6, l = t & 63, quad = l >> 4, l15 = l & 15;

    // Q fragment in registers (B-operand; 16 query rows per wave)
    bf16x8 qf[2];
    {
        int row = q0 + w*16 + l15;
        if (row > NSEQ - 1) row = NSEQ - 1;
        #pragma unroll
        for (int ks = 0; ks < 2; ++ks)
            qf[ks] = *(const bf16x8*)&Kh[(size_t)row * HD + ks*32 + quad*8];
    }

    const int qg = q0 + w*16 + l15;
    const int srow = t >> 3;          // 0..63
    const int scol = (t & 7) * 8;     // 0..56
    const int sPr  = (w*16 + l15) * 64;
    const int sw   = l15 & 7;

    f32x4 Oacc[4] = {};
    float ps[4] = {0.f, 0.f, 0.f, 0.f};

    // initial prefetch (tile 0)
    uint4 kv, vv;
    f32x4 bias_pf[4];
    {
        kv = *(const uint4*)&Kh[(size_t)srow * HD + scol];
        vv = *(const uint4*)&Vh[(size_t)srow * HD + scol];
        #pragma unroll
        for (int kt = 0; kt < 4; ++kt)
            bias_pf[kt] = *(const f32x4*)&Bias[(size_t)qg * BK_COLS + kt*16 + quad*4];
    }

    for (int j0 = 0; j0 < NSEQ; j0 += 64) {
        *(uint4*)&sK[srow][scol] = kv;
        {   // transpose V rows into sVT[d][j_local]
            bf16 vals[8];
            *(uint4*)vals = vv;
            #pragma unroll
            for (int e = 0; e < 8; ++e)
                sVT[scol + e][srow] = vals[e];
        }
        f32x4 sacc[4];
        #pragma unroll
        for (int kt = 0; kt < 4; ++kt) sacc[kt] = bias_pf[kt];
        __syncthreads();

        // prefetch next tile (consumed next iteration)
        {
            int jn = j0 + 64; if (jn >= NSEQ) jn = j0;
            int rk = jn + srow; if (rk > NSEQ - 1) rk = NSEQ - 1;
            kv = *(const uint4*)&Kh[(size_t)rk * HD + scol];
            vv = *(const uint4*)&Vh[(size_t)rk * HD + scol];
            #pragma unroll
            for (int kt = 0; kt < 4; ++kt)
                bias_pf[kt] = *(const f32x4*)&Bias[(size_t)qg * BK_COLS + jn + kt*16 + quad*4];
        }

        // S^T = K' * Q'^T  (A = keys from LDS, B = query frag in regs)
        #pragma unroll
        for (int ks = 0; ks < 2; ++ks) {
            bf16x8 af[4];
            #pragma unroll
            for (int kt = 0; kt < 4; ++kt)
                af[kt] = *(const bf16x8*)&sK[kt*16 + l15][ks*32 + quad*8];
            #pragma unroll
            for (int kt = 0; kt < 4; ++kt)
                sacc[kt] = __builtin_amdgcn_mfma_f32_16x16x32_bf16(af[kt], qf[ks], sacc[kt], 0, 0, 0);
        }

        // P = exp(S); swizzled b64 store (4 keys/lane)
        #pragma unroll
        for (int kt = 0; kt < 4; ++kt) {
            float p0 = __expf(sacc[kt][0]);
            float p1 = __expf(sacc[kt][1]);
            float p2 = __expf(sacc[kt][2]);
            float p3 = __expf(sacc[kt][3]);
            ps[kt] += (p0 + p1) + (p2 + p3);
            bf16x4 pv = { (bf16)p0, (bf16)p1, (bf16)p2, (bf16)p3 };
            int g = (kt*2 + (quad >> 1)) ^ sw;
            *(bf16x4*)&sP[sPr + g*8 + (quad & 1)*4] = pv;
        }

        // O += P V
        #pragma unroll
        for (int ks = 0; ks < 2; ++ks) {
            bf16x8 ap, bv[4];
            ap = *(const bf16x8*)&sP[sPr + (((ks*4 + quad) ^ sw) * 8)];
            #pragma unroll
            for (int dt = 0; dt < 4; ++dt)
                bv[dt] = *(const bf16x8*)&sVT[dt*16 + l15][ks*32 + quad*8];
            #pragma unroll
            for (int dt = 0; dt < 4; ++dt)
                Oacc[dt] = __builtin_amdgcn_mfma_f32_16x16x32_bf16(ap, bv[dt], Oacc[dt], 0, 0, 0);
        }
        __syncthreads();
    }

    // row sums: reduce across quads, distribute via LDS
    {
        float s = (ps[0] + ps[1]) + (ps[2] + ps[3]);
        s += __shfl_xor(s, 16, 64);
        s += __shfl_xor(s, 32, 64);
        if (l < 16) sL[w*16 + l] = s;
    }
    __syncthreads();

    #pragma unroll
    for (int r = 0; r < 4; ++r) {
        int g = q0 + w*16 + quad*4 + r;
        if (g >= NSEQ) continue;
        float inv = 1.f / sL[w*16 + quad*4 + r];
        size_t base = ((size_t)(b * NSEQ) + g) * CDIM + h * HD;
        #pragma unroll
        for (int dt = 0; dt < 4; ++dt)
            Hout[base + dt*16 + l15] = (bf16)(Oacc[dt][r] * inv);
    }
}

extern "C" void kernel_launch(void* const* d_in, const int* in_sizes, int n_in,
                              void* d_out, int out_size, void* d_ws, size_t ws_size,
                              hipStream_t stream) {
    const float* x      = (const float*)d_in[0];
    const float* qkv_w  = (const float*)d_in[1];
    const float* qkv_b  = (const float*)d_in[2];
    const float* proj_w = (const float*)d_in[3];
    const float* proj_b = (const float*)d_in[4];
    float* out = (float*)d_out;

    char* ws = (char*)d_ws;
    const size_t XBF_BYTES   = (size_t)MROWS * CDIM * 2;
    const size_t WKV_BYTES   = (size_t)2 * CDIM * CDIM * 2;
    const size_t PW_BYTES    = (size_t)CDIM * CDIM * 2;
    const size_t KBF_BYTES   = (size_t)BATCH * NHEADS * NSEQ * HD * 2;

    bf16* x_bf   = (bf16*)ws;
    bf16* wkv_bf = (bf16*)(ws + XBF_BYTES);
    bf16* pw_bf  = (bf16*)(ws + XBF_BYTES + WKV_BYTES);
    bf16* k_bf   = (bf16*)(ws + XBF_BYTES + WKV_BYTES + PW_BYTES);
    bf16* v_bf   = (bf16*)(ws + XBF_BYTES + WKV_BYTES + PW_BYTES + KBF_BYTES);
    float* bias_t= (float*)(ws + XBF_BYTES + WKV_BYTES + PW_BYTES + KBF_BYTES + KBF_BYTES);

    // fused prep: bias table + all casts
    {
        int total = BQ_ROWS * BK_COLS + MROWS * CDIM / 4
                  + 2 * CDIM * CDIM / 4 + CDIM * CDIM / 4;
        prep_kernel<<<dim3((total + 255) / 256), dim3(256), 0, stream>>>(
            x, qkv_w + (size_t)CDIM * CDIM, proj_w, x_bf, wkv_bf, pw_bf, bias_t);
    }

    // qkv GEMM (k & v only): M=8256, N=1536, K=768
    {
        dim3 grid(1536 / 128, (MROWS + 127) / 128);
        gemm_nt<1><<<grid, dim3(256), 0, stream>>>(x_bf, wkv_bf, qkv_b + CDIM,
                                                   nullptr, k_bf, v_bf,
                                                   MROWS, 1536, CDIM);
    }

    // attention -> hidden (reuse x_bf buffer); grid (bh, qtile) for XCD locality
    {
        dim3 grid(BATCH * NHEADS, (NSEQ + 127) / 128);
        attn_kernel<<<grid, dim3(512), 0, stream>>>(k_bf, v_bf, bias_t, x_bf);
    }

    // proj GEMM: out = hidden @ proj_w^T + proj_b, fp32 out
    {
        dim3 grid(CDIM / 128, (MROWS + 127) / 128);
        gemm_nt<0><<<grid, dim3(256), 0, stream>>>(x_bf, pw_bf, proj_b,
                                                   out, nullptr, nullptr,
                                                   MROWS, CDIM, CDIM);
    }
}